// Round 1
// baseline (267.158 us; speedup 1.0000x reference)
//
#include <hip/hip_runtime.h>
#include <math.h>

// Problem constants (reference: B=2, N=512, D=64)
#define BB 2
#define NN2 512
#define DD 64
#define EPS 1e-5f

// ---------------- workspace layout (float offsets) ----------------
#define OFF_W1TA  0        // [64][128]  s1-folded W1[:, :64] transposed -> [d][o]
#define OFF_W1TB  8192     // [64][128]  s1-folded W1[:, 64:] transposed
#define OFF_VBIAS 16384    // [128]      s1*b1 + be1 - m1*s1
#define OFF_W2T   16512    // [128][64]  s2-folded W2 transposed -> [k][o]
#define OFF_C2    24704    // [64]
#define OFF_W3T   24768    // [64][32]   s3-folded W3 transposed -> [k][o]
#define OFF_C3    26816    // [32]
#define OFF_U     26848    // [B*N][128]
#define OFF_V     157920   // [B*N][128]
#define OFF_NF    288992   // [B*N][64]  normalized features
#define OFF_RAWL  354528   // [B][N][N]  raw MLP logits
#define OFF_NVALID 878816  // [B] ints

// ---------------- P1: fold weights + n_valid ----------------
__global__ __launch_bounds__(256) void prep_fold(
    const float* __restrict__ W1, const float* __restrict__ b1,
    const float* __restrict__ W2, const float* __restrict__ b2,
    const float* __restrict__ W3, const float* __restrict__ b3,
    const float* __restrict__ g1, const float* __restrict__ be1,
    const float* __restrict__ m1, const float* __restrict__ v1,
    const float* __restrict__ g2, const float* __restrict__ be2,
    const float* __restrict__ m2, const float* __restrict__ v2,
    const float* __restrict__ g3, const float* __restrict__ be3,
    const float* __restrict__ m3, const float* __restrict__ v3,
    const int* __restrict__ masks,
    float* __restrict__ ws, int* __restrict__ nvalid)
{
    const int blk = blockIdx.x, t = threadIdx.x;
    if (blk < 8) {
        // W2t[k][o] = W2[o][k] * s2[o] : 8192 elems, 8 blocks x 256 x 4
        int e0 = blk * 1024 + t * 4;
        #pragma unroll
        for (int q = 0; q < 4; q++) {
            int e = e0 + q;
            int o = e & 63, k = e >> 6;
            float s = g2[o] * rsqrtf(v2[o] + EPS);
            ws[OFF_W2T + e] = W2[o * 128 + k] * s;
        }
    } else if (blk < 10) {
        // W3t[k][o] = W3[o][k] * s3[o] : 2048 elems, 2 blocks x 256 x 4
        int e0 = (blk - 8) * 1024 + t * 4;
        #pragma unroll
        for (int q = 0; q < 4; q++) {
            int e = e0 + q;
            if (e < 2048) {
                int o = e & 31, k = e >> 5;
                float s = g3[o] * rsqrtf(v3[o] + EPS);
                ws[OFF_W3T + e] = W3[o * 64 + k] * s;
            }
        }
    } else if (blk < 26) {
        // W1ta/W1tb (16384 elems): [d][o] = W1[o][d]*s1[o] (first/second half of d)
        int e0 = (blk - 10) * 1024 + t * 4;
        #pragma unroll
        for (int q = 0; q < 4; q++) {
            int e = e0 + q;
            if (e < 8192) {
                int d = e >> 7, o = e & 127;
                float s = g1[o] * rsqrtf(v1[o] + EPS);
                ws[OFF_W1TA + e] = W1[o * 128 + d] * s;
            } else {
                int eb = e - 8192;
                int d = eb >> 7, o = eb & 127;
                float s = g1[o] * rsqrtf(v1[o] + EPS);
                ws[OFF_W1TB + eb] = W1[o * 128 + 64 + d] * s;
            }
        }
    } else if (blk == 26) {
        // Vbias(128), c2(64), c3(32)
        if (t < 128) {
            float s = g1[t] * rsqrtf(v1[t] + EPS);
            ws[OFF_VBIAS + t] = s * b1[t] + be1[t] - m1[t] * s;
        } else if (t < 192) {
            int o = t - 128;
            float s = g2[o] * rsqrtf(v2[o] + EPS);
            ws[OFF_C2 + o] = b2[o] * s + be2[o] - m2[o] * s;
        } else if (t < 224) {
            int o = t - 192;
            float s = g3[o] * rsqrtf(v3[o] + EPS);
            ws[OFF_C3 + o] = b3[o] * s + be3[o] - m3[o] * s;
        }
    } else {
        // n_valid per batch: wave w handles batch w
        int w = t >> 6, l = t & 63;
        if (w < BB) {
            int s = 0;
            #pragma unroll
            for (int q = 0; q < 8; q++) s += (masks[w * NN2 + q * 64 + l] != 0) ? 1 : 0;
            #pragma unroll
            for (int off = 1; off < 64; off <<= 1) s += __shfl_xor(s, off);
            if (l == 0) nvalid[w] = s;
        }
    }
}

// ---------------- P2: per-node U/V precompute ----------------
__global__ __launch_bounds__(128) void prep_uv(
    const float* __restrict__ feat,
    const float* __restrict__ W1ta, const float* __restrict__ W1tb,
    const float* __restrict__ Vbias,
    float* __restrict__ U, float* __restrict__ V)
{
    __shared__ float F[4][64];
    const int nb = blockIdx.x * 4;   // 256 blocks cover 1024 nodes
    const int t = threadIdx.x;       // 128
    if (t < 64) {
        int r = t >> 4, c = (t & 15) * 4;
        *(float4*)&F[r][c] = *(const float4*)&feat[(nb + r) * 64 + c];
    }
    __syncthreads();
    const int o = t;
    float aU[4] = {0.f, 0.f, 0.f, 0.f};
    float aV[4] = {0.f, 0.f, 0.f, 0.f};
    for (int d = 0; d < 64; d++) {
        float wa = W1ta[d * 128 + o];
        float wb = W1tb[d * 128 + o];
        #pragma unroll
        for (int n = 0; n < 4; n++) {
            aU[n] = fmaf(F[n][d], wa, aU[n]);
            aV[n] = fmaf(F[n][d], wb, aV[n]);
        }
    }
    float vb = Vbias[o];
    #pragma unroll
    for (int n = 0; n < 4; n++) {
        U[(nb + n) * 128 + o] = aU[n];
        V[(nb + n) * 128 + o] = aV[n] + vb;
    }
}

// ---------------- P3: normalized features ----------------
__global__ __launch_bounds__(256) void prep_nf(
    const float* __restrict__ feat, float* __restrict__ nf)
{
    const int t = threadIdx.x;
    const int w = t >> 6, l = t & 63;
    const int node = blockIdx.x * 4 + w;   // 256 blocks x 4 waves = 1024 nodes
    float x = feat[node * 64 + l];
    float ss = x * x;
    #pragma unroll
    for (int off = 1; off < 64; off <<= 1) ss += __shfl_xor(ss, off);
    float inv = 1.0f / fmaxf(sqrtf(ss), 1e-12f);
    nf[node * 64 + l] = x * inv;
}

// ---------------- Main: per-pair MLP -> raw logits ----------------
__global__ __launch_bounds__(256) void mlp_main(
    const float* __restrict__ U, const float* __restrict__ V,
    const float* __restrict__ W2t, const float* __restrict__ c2,
    const float* __restrict__ W3t, const float* __restrict__ c3,
    const float* __restrict__ W4, const float* __restrict__ b4,
    float* __restrict__ rawL)
{
    // stride 132: row bank-offset 4 -> worst 2-way LDS aliasing (free), float4-aligned
    __shared__ float Ut[16][132];
    __shared__ float Vt[16][132];
    const int t = threadIdx.x;
    const int b = blockIdx.z;
    const int i0 = blockIdx.y * 16, j0 = blockIdx.x * 16;
    {
        int r = t >> 4, c = (t & 15) * 8;
        float4 a0 = *(const float4*)&U[(b * NN2 + i0 + r) * 128 + c];
        float4 a1 = *(const float4*)&U[(b * NN2 + i0 + r) * 128 + c + 4];
        *(float4*)&Ut[r][c]     = a0;
        *(float4*)&Ut[r][c + 4] = a1;
        float4 v0 = *(const float4*)&V[(b * NN2 + j0 + r) * 128 + c];
        float4 v1 = *(const float4*)&V[(b * NN2 + j0 + r) * 128 + c + 4];
        *(float4*)&Vt[r][c]     = v0;
        *(float4*)&Vt[r][c + 4] = v1;
    }
    __syncthreads();
    const int i = t >> 4, j = t & 15;

    // layer 2: acc[o] = c2[o] + sum_k W2t[k][o] * relu(U[i][k]+V[j][k])
    float acc[64];
    #pragma unroll
    for (int o = 0; o < 64; o++) acc[o] = c2[o];
    for (int k = 0; k < 128; k += 4) {
        float4 uk = *(const float4*)&Ut[i][k];
        float4 vk = *(const float4*)&Vt[j][k];
        float h[4];
        h[0] = fmaxf(uk.x + vk.x, 0.f);
        h[1] = fmaxf(uk.y + vk.y, 0.f);
        h[2] = fmaxf(uk.z + vk.z, 0.f);
        h[3] = fmaxf(uk.w + vk.w, 0.f);
        const float* w = &W2t[k * 64];   // uniform address -> scalar loads
        #pragma unroll
        for (int kk = 0; kk < 4; kk++) {
            #pragma unroll
            for (int o = 0; o < 64; o++)
                acc[o] = fmaf(w[kk * 64 + o], h[kk], acc[o]);
        }
    }
    // layer 3 (fully unrolled so acc[k] stays in registers)
    float a3[32];
    #pragma unroll
    for (int o = 0; o < 32; o++) a3[o] = c3[o];
    #pragma unroll
    for (int k = 0; k < 64; k++) {
        float hk = fmaxf(acc[k], 0.f);
        #pragma unroll
        for (int o = 0; o < 32; o++)
            a3[o] = fmaf(W3t[k * 32 + o], hk, a3[o]);
    }
    // layer 4
    float lg = b4[0];
    #pragma unroll
    for (int k = 0; k < 32; k++) lg = fmaf(W4[k], fmaxf(a3[k], 0.f), lg);

    rawL[(size_t)(b * NN2 + i0 + i) * NN2 + j0 + j] = lg;
}

// ---------------- Post: symmetrize + cosine + sigmoid + mask ----------------
__global__ __launch_bounds__(256) void post_kernel(
    const float* __restrict__ rawL, const float* __restrict__ nf,
    const int* __restrict__ masks, const int* __restrict__ nvalid,
    float* __restrict__ outA, float* __restrict__ outL)
{
    __shared__ float nfI[16][68], nfJ[16][68];
    __shared__ float Lt[16][17];
    __shared__ int mI[16], mJ[16];
    const int t = threadIdx.x;
    const int b = blockIdx.z, i0 = blockIdx.y * 16, j0 = blockIdx.x * 16;
    {
        int r = t >> 4, c = (t & 15) * 4;
        *(float4*)&nfI[r][c] = *(const float4*)&nf[(b * NN2 + i0 + r) * 64 + c];
        *(float4*)&nfJ[r][c] = *(const float4*)&nf[(b * NN2 + j0 + r) * 64 + c];
    }
    {
        int r = t >> 4, c = t & 15;   // transpose tile rawL[b][j0+r][i0+c]
        Lt[r][c] = rawL[(size_t)(b * NN2 + j0 + r) * NN2 + i0 + c];
    }
    if (t < 16) mI[t] = masks[b * NN2 + i0 + t];
    else if (t < 32) mJ[t - 16] = masks[b * NN2 + j0 + (t - 16)];
    __syncthreads();

    const int i = t >> 4, j = t & 15;
    const int gi = i0 + i, gj = j0 + j;
    float Lij = rawL[(size_t)(b * NN2 + gi) * NN2 + gj];
    float Lji = Lt[j][i];
    float Ls = (gi == gj) ? -10.0f : 0.5f * (Lij + Lji);

    float sim = 0.f;
    #pragma unroll
    for (int d = 0; d < 64; d += 4) {
        float4 x = *(const float4*)&nfI[i][d];
        float4 y = *(const float4*)&nfJ[j][d];
        sim = fmaf(x.x, y.x, sim);
        sim = fmaf(x.y, y.y, sim);
        sim = fmaf(x.z, y.z, sim);
        sim = fmaf(x.w, y.w, sim);
    }
    float logit = (Ls + 2.0f * sim) * 2.0f;   // / 0.5 temperature
    float p = 1.0f / (1.0f + expf(-logit));
    p = (p > 0.6f) ? p * 1.2f : p * 0.8f;
    p = fminf(fmaxf(p, 0.0f), 1.0f);
    bool pm = (mI[i] != 0) && (mJ[j] != 0) && (nvalid[b] > 1);
    size_t idx = (size_t)(b * NN2 + gi) * NN2 + gj;
    outA[idx] = pm ? p : 0.0f;
    outL[idx] = pm ? logit : 0.0f;
}

// ---------------- launch ----------------
extern "C" void kernel_launch(void* const* d_in, const int* in_sizes, int n_in,
                              void* d_out, int out_size, void* d_ws, size_t ws_size,
                              hipStream_t stream)
{
    const float* feat = (const float*)d_in[0];
    const int*   masks = (const int*)d_in[1];
    const float* W1 = (const float*)d_in[2];
    const float* b1 = (const float*)d_in[3];
    const float* W2 = (const float*)d_in[4];
    const float* b2 = (const float*)d_in[5];
    const float* W3 = (const float*)d_in[6];
    const float* b3 = (const float*)d_in[7];
    const float* W4 = (const float*)d_in[8];
    const float* b4 = (const float*)d_in[9];
    const float* g1 = (const float*)d_in[10];
    const float* be1 = (const float*)d_in[11];
    const float* m1 = (const float*)d_in[12];
    const float* v1 = (const float*)d_in[13];
    const float* g2 = (const float*)d_in[14];
    const float* be2 = (const float*)d_in[15];
    const float* m2 = (const float*)d_in[16];
    const float* v2 = (const float*)d_in[17];
    const float* g3 = (const float*)d_in[18];
    const float* be3 = (const float*)d_in[19];
    const float* m3 = (const float*)d_in[20];
    const float* v3 = (const float*)d_in[21];

    float* ws = (float*)d_ws;
    float* W1ta  = ws + OFF_W1TA;
    float* W1tb  = ws + OFF_W1TB;
    float* Vbias = ws + OFF_VBIAS;
    float* W2t   = ws + OFF_W2T;
    float* c2    = ws + OFF_C2;
    float* W3t   = ws + OFF_W3T;
    float* c3    = ws + OFF_C3;
    float* U     = ws + OFF_U;
    float* V     = ws + OFF_V;
    float* nf    = ws + OFF_NF;
    float* rawL  = ws + OFF_RAWL;
    int*   nvalid = (int*)(ws + OFF_NVALID);

    float* outA = (float*)d_out;
    float* outL = outA + (size_t)BB * NN2 * NN2;

    prep_fold<<<28, 256, 0, stream>>>(W1, b1, W2, b2, W3, b3,
                                      g1, be1, m1, v1, g2, be2, m2, v2,
                                      g3, be3, m3, v3, masks, ws, nvalid);
    prep_uv<<<256, 128, 0, stream>>>(feat, W1ta, W1tb, Vbias, U, V);
    prep_nf<<<256, 256, 0, stream>>>(feat, nf);
    dim3 grid(32, 32, 2);
    mlp_main<<<grid, 256, 0, stream>>>(U, V, W2t, c2, W3t, c3, W4, b4, rawL);
    post_kernel<<<grid, 256, 0, stream>>>(rawL, nf, masks, nvalid, outA, outL);
}